// Round 6
// baseline (295.791 us; speedup 1.0000x reference)
//
#include <hip/hip_runtime.h>

#define NNODES 50000
#define NEDGES 800000
#define NGRAPHS 2048

typedef __attribute__((ext_vector_type(8))) short bf16x8;
typedef __attribute__((ext_vector_type(4))) float f32x4;

__device__ __forceinline__ float bf2f(ushort u) {
    return __uint_as_float(((uint)u) << 16);
}
__device__ __forceinline__ ushort f2bf(float f) {
    uint u = __float_as_uint(f);
    return (ushort)((u + 0x7fff + ((u >> 16) & 1)) >> 16);  // RNE
}

// ---------------- degree ----------------
__global__ void deg_count(const int* __restrict__ dst, int* __restrict__ cnt, int E) {
    int e = blockIdx.x * blockDim.x + threadIdx.x;
    if (e < E) atomicAdd(&cnt[dst[e]], 1);
}

// ---------------- CSR build ----------------
__global__ void block_scan(const int* __restrict__ cnt, int* __restrict__ lp,
                           int* __restrict__ bsum, int M) {
    __shared__ int s[256];
    int t = threadIdx.x;
    int n = blockIdx.x * 256 + t;
    int v = (n < M) ? cnt[n] : 0;
    s[t] = v;
    __syncthreads();
    #pragma unroll
    for (int off = 1; off < 256; off <<= 1) {
        int u = (t >= off) ? s[t - off] : 0;
        __syncthreads();
        s[t] += u;
        __syncthreads();
    }
    if (n < M) lp[n] = s[t] - v;
    if (t == 255) bsum[blockIdx.x] = s[255];
}

__global__ void scan_bsum(int* __restrict__ bsum, int NB) {
    __shared__ int s[256];
    int t = threadIdx.x;
    int v = (t < NB) ? bsum[t] : 0;
    s[t] = v;
    __syncthreads();
    #pragma unroll
    for (int off = 1; off < 256; off <<= 1) {
        int u = (t >= off) ? s[t - off] : 0;
        __syncthreads();
        s[t] += u;
        __syncthreads();
    }
    if (t < NB) bsum[t] = s[t] - v;
}

// rowptr finalize + cursor init + dis = rsqrt(deg+1) fused
__global__ void finalize_rowptr(int* __restrict__ rowptr, int* __restrict__ cursor,
                                const int* __restrict__ bsum, const int* __restrict__ cnt,
                                float* __restrict__ dis, int M, int E) {
    int n = blockIdx.x * blockDim.x + threadIdx.x;
    if (n < M) {
        int v = rowptr[n] + bsum[n >> 8];
        rowptr[n] = v;
        cursor[n] = v;
        dis[n] = rsqrtf((float)(cnt[n] + 1));
    }
    if (n == 0) rowptr[M] = E;
}

// packed (src, norm) single 8B store per edge
__global__ void fill_csr(const int* __restrict__ src, const int* __restrict__ dst,
                         const float* __restrict__ dis, int* __restrict__ cursor,
                         int2* __restrict__ csr, int E) {
    int e = blockIdx.x * blockDim.x + threadIdx.x;
    if (e >= E) return;
    int s = src[e], d = dst[e];
    int pos = atomicAdd(&cursor[d], 1);
    csr[pos] = make_int2(s, __float_as_int(dis[s] * dis[d]));
}

// ---------------- input cast / weight prep ----------------
__global__ void cast_x(const float* __restrict__ x, ushort* __restrict__ xb,
                       int M, int K, int Kp) {
    int idx = blockIdx.x * blockDim.x + threadIdx.x;
    if (idx >= M * Kp) return;
    int n = idx / Kp, k = idx % Kp;
    xb[idx] = (k < K) ? f2bf(x[(size_t)n * K + k]) : (ushort)0;
}

// Wt[n][k] = W[k][n], bf16, zero-padded to [Np][Kp]
__global__ void prep_w(const float* __restrict__ W, ushort* __restrict__ Wt,
                       int K, int N, int Kp, int Np) {
    int idx = blockIdx.x * blockDim.x + threadIdx.x;
    if (idx >= Kp * Np) return;
    int n = idx / Kp, k = idx % Kp;
    Wt[idx] = (k < K && n < N) ? f2bf(W[(size_t)k * N + n]) : (ushort)0;
}

// ---------------- ILP gather: lanes = (sub-edge, uint4-chunk) ----------------
// U blocks of SUB edges per outer step; phases separated so all valid row
// loads issue before any accumulate waits (wave-uniform guards = scalar
// branches, no vmcnt dependency).
__device__ __forceinline__ void acc8(float* acc, uint4 v, float nm) {
    acc[0] += bf2f((ushort)(v.x & 0xffff)) * nm;
    acc[1] += bf2f((ushort)(v.x >> 16)) * nm;
    acc[2] += bf2f((ushort)(v.y & 0xffff)) * nm;
    acc[3] += bf2f((ushort)(v.y >> 16)) * nm;
    acc[4] += bf2f((ushort)(v.z & 0xffff)) * nm;
    acc[5] += bf2f((ushort)(v.z >> 16)) * nm;
    acc[6] += bf2f((ushort)(v.w & 0xffff)) * nm;
    acc[7] += bf2f((ushort)(v.w >> 16)) * nm;
}

template <int CH, int SUB, int U, int CHOUT>
__global__ __launch_bounds__(256) void gather_ilp(const uint4* __restrict__ h,
                                                  const int* __restrict__ rowptr,
                                                  const int2* __restrict__ csr,
                                                  const float* __restrict__ dis,
                                                  uint4* __restrict__ agg) {
    int node = blockIdx.x * 4 + (threadIdx.x >> 6);
    if (node >= NNODES) return;
    int lane = threadIdx.x & 63;
    int sub = lane / CH;
    int ch = lane % CH;
    bool active = sub < SUB;

    float acc[8] = {};
    int beg = rowptr[node], end = rowptr[node + 1];
    for (int i = beg; i < end; i += U * SUB) {
        // phase 1: edge records (up to U independent 8B loads)
        int2 ev[U];
        #pragma unroll
        for (int u = 0; u < U; ++u) {
            ev[u] = make_int2(0, 0);
            if (i + u * SUB < end) {                 // wave-uniform
                int e = i + u * SUB + sub;
                if (active && e < end) ev[u] = csr[e];
            }
        }
        // phase 2: rows (up to U independent 16B loads; inactive lanes
        // read row 0 broadcast with nm=0 — harmless)
        uint4 av[U];
        #pragma unroll
        for (int u = 0; u < U; ++u) {
            if (i + u * SUB < end)
                av[u] = h[(size_t)ev[u].x * CH + ch];
        }
        // phase 3: accumulate
        #pragma unroll
        for (int u = 0; u < U; ++u) {
            if (i + u * SUB < end)
                acc8(acc, av[u], __int_as_float(ev[u].y));
        }
    }

    // reduce partials across sub groups (read-only sources -> no contamination)
    float tot[8];
    #pragma unroll
    for (int j = 0; j < 8; ++j) tot[j] = acc[j];
    #pragma unroll
    for (int sb = 1; sb < SUB; ++sb) {
        int srcLane = ch + sb * CH;
        #pragma unroll
        for (int j = 0; j < 8; ++j) tot[j] += __shfl(acc[j], srcLane);
    }

    if (lane < CHOUT) {
        uint4 o = make_uint4(0, 0, 0, 0);
        if (lane < CH) {
            float di = dis[node];
            float d2 = di * di;
            uint4 hs = h[(size_t)node * CH + lane];
            tot[0] += bf2f((ushort)(hs.x & 0xffff)) * d2;
            tot[1] += bf2f((ushort)(hs.x >> 16)) * d2;
            tot[2] += bf2f((ushort)(hs.y & 0xffff)) * d2;
            tot[3] += bf2f((ushort)(hs.y >> 16)) * d2;
            tot[4] += bf2f((ushort)(hs.z & 0xffff)) * d2;
            tot[5] += bf2f((ushort)(hs.z >> 16)) * d2;
            tot[6] += bf2f((ushort)(hs.w & 0xffff)) * d2;
            tot[7] += bf2f((ushort)(hs.w >> 16)) * d2;
            o.x = (uint)f2bf(tot[0]) | ((uint)f2bf(tot[1]) << 16);
            o.y = (uint)f2bf(tot[2]) | ((uint)f2bf(tot[3]) << 16);
            o.z = (uint)f2bf(tot[4]) | ((uint)f2bf(tot[5]) << 16);
            o.w = (uint)f2bf(tot[6]) | ((uint)f2bf(tot[7]) << 16);
        }
        agg[(size_t)node * CHOUT + lane] = o;
    }
}

// ---------------- MFMA bf16 GEMM: C = epi(A[M][Kp] @ Wt[Np][Kp]^T) ----------------
template <int EPI>
__global__ __launch_bounds__(256) void gemm_mfma(const ushort* __restrict__ A,
                                                 const ushort* __restrict__ Bt,
                                                 ushort* __restrict__ Cb,
                                                 float* __restrict__ Cf,
                                                 const float* __restrict__ bias,
                                                 const float* __restrict__ addend,
                                                 int M, int Kp, int Np, int Nreal) {
    __shared__ ushort Asl[64 * 32];
    __shared__ ushort Bsl[64 * 32];
    const int tid = threadIdx.x;
    const int lane = tid & 63;
    const int wid = tid >> 6;
    const int wm = (wid >> 1) * 32, wn = (wid & 1) * 32;
    const int bm = blockIdx.x * 64, bn = blockIdx.y * 64;

    const int sr = tid >> 2;
    const int sc = tid & 3;
    const int swz = sc ^ ((sr >> 1) & 3);
    const int lc = lane >> 4;

    f32x4 acc[2][2] = {};
    for (int k0 = 0; k0 < Kp; k0 += 32) {
        bf16x8 av = {};
        int gr = bm + sr;
        if (gr < M) av = *(const bf16x8*)&A[(size_t)gr * Kp + k0 + sc * 8];
        *(bf16x8*)&Asl[sr * 32 + swz * 8] = av;
        bf16x8 bv = {};
        int gn = bn + sr;
        if (gn < Np) bv = *(const bf16x8*)&Bt[(size_t)gn * Kp + k0 + sc * 8];
        *(bf16x8*)&Bsl[sr * 32 + swz * 8] = bv;
        __syncthreads();
        bf16x8 af[2], bfr[2];
        #pragma unroll
        for (int m = 0; m < 2; ++m) {
            int r = wm + m * 16 + (lane & 15);
            int pc = lc ^ ((r >> 1) & 3);
            af[m] = *(const bf16x8*)&Asl[r * 32 + pc * 8];
        }
        #pragma unroll
        for (int n = 0; n < 2; ++n) {
            int r = wn + n * 16 + (lane & 15);
            int pc = lc ^ ((r >> 1) & 3);
            bfr[n] = *(const bf16x8*)&Bsl[r * 32 + pc * 8];
        }
        #pragma unroll
        for (int m = 0; m < 2; ++m)
            #pragma unroll
            for (int n = 0; n < 2; ++n)
                acc[m][n] = __builtin_amdgcn_mfma_f32_16x16x32_bf16(af[m], bfr[n], acc[m][n], 0, 0, 0);
        __syncthreads();
    }
    #pragma unroll
    for (int m = 0; m < 2; ++m) {
        #pragma unroll
        for (int n = 0; n < 2; ++n) {
            int gc = bn + wn + n * 16 + (lane & 15);
            #pragma unroll
            for (int j = 0; j < 4; ++j) {
                int gr = bm + wm + m * 16 + (lane >> 4) * 4 + j;
                if (gr >= M) continue;
                float v = acc[m][n][j];
                if (EPI == 0) {
                    if (gc < Np) {
                        float o = (gc < Nreal) ? fmaxf(v + bias[gc], 0.f) : 0.f;
                        Cb[(size_t)gr * Np + gc] = f2bf(o);
                    }
                } else {
                    if (gc < Nreal) {
                        float o = fmaxf(v + bias[gc], 0.f) + addend[(size_t)gr * Nreal + gc];
                        Cf[(size_t)gr * Nreal + gc] = o;
                    }
                }
            }
        }
    }
}

// ---------------- per-graph segment bounds (batch is sorted) ----------------
__global__ void graph_bounds(const int* __restrict__ batch, int* __restrict__ gstart,
                             int M, int G) {
    int n = blockIdx.x * blockDim.x + threadIdx.x;
    if (n >= M) return;
    int b = batch[n];
    int bp = (n == 0) ? -1 : batch[n - 1];
    for (int gg = bp + 1; gg <= b; ++gg) gstart[gg] = n;
    if (n == M - 1) {
        for (int gg = b + 1; gg <= G; ++gg) gstart[gg] = M;
    }
}

// ---------------- segmented max pool: block per graph, bf16 out ----------------
__global__ void pool_max_seg(const uint* __restrict__ h3, const int* __restrict__ gstart,
                             uint* __restrict__ gb, int PAIRS) {
    int g = blockIdx.x;
    int s = gstart[g], e = gstart[g + 1];
    for (int p = threadIdx.x; p < PAIRS; p += blockDim.x) {
        float mL = 0.f, mH = 0.f;  // h3 >= 0; empty graph -> 0 (isfinite guard)
        for (int n = s; n < e; ++n) {
            uint v = h3[(size_t)n * PAIRS + p];
            mL = fmaxf(mL, bf2f((ushort)(v & 0xffff)));
            mH = fmaxf(mH, bf2f((ushort)(v >> 16)));
        }
        gb[(size_t)g * PAIRS + p] = (uint)f2bf(mL) | ((uint)f2bf(mH) << 16);
    }
}

extern "C" void kernel_launch(void* const* d_in, const int* in_sizes, int n_in,
                              void* d_out, int out_size, void* d_ws, size_t ws_size,
                              hipStream_t stream) {
    const float* x     = (const float*)d_in[0];
    const int*   eidx  = (const int*)d_in[1];
    const int*   batch = (const int*)d_in[2];
    const float* drug2 = (const float*)d_in[3];
    const float* W1 = (const float*)d_in[4];
    const float* b1 = (const float*)d_in[5];
    const float* W2 = (const float*)d_in[6];
    const float* b2 = (const float*)d_in[7];
    const float* W3 = (const float*)d_in[8];
    const float* b3 = (const float*)d_in[9];
    const float* Wfc = (const float*)d_in[10];
    const float* bfc = (const float*)d_in[11];
    float* out = (float*)d_out;

    const int M = NNODES, E = NEDGES, G = NGRAPHS;
    const int F1 = 78, F2 = 156, F3 = 312, FC = 489;
    const int Kp1 = 96, Np1 = 80;
    const int Kp2 = 96, Np2 = 160;
    const int Kp3 = 160, Np3 = 320;
    const int Kpf = 320, Npf = 496;

    const int* src = eidx;
    const int* dst = eidx + E;
    const int NB = (M + 255) / 256;

    char* ws = (char*)d_ws;
    size_t off = 0;
    auto alloc = [&](size_t bytes) {
        void* p = ws + off;
        off += (bytes + 255) & ~(size_t)255;
        return p;
    };
    ushort* xb   = (ushort*)alloc((size_t)M * Kp1 * 2);
    ushort* h1   = (ushort*)alloc((size_t)M * Np1 * 2);
    ushort* h2   = (ushort*)alloc((size_t)M * Np2 * 2);
    ushort* h3   = (ushort*)alloc((size_t)M * Np3 * 2);
    ushort* agg  = (ushort*)alloc((size_t)M * Kp3 * 2);
    ushort* W1t  = (ushort*)alloc((size_t)Np1 * Kp1 * 2);
    ushort* W2t  = (ushort*)alloc((size_t)Np2 * Kp2 * 2);
    ushort* W3t  = (ushort*)alloc((size_t)Np3 * Kp3 * 2);
    ushort* Wfct = (ushort*)alloc((size_t)Npf * Kpf * 2);
    ushort* gb   = (ushort*)alloc((size_t)G * Kpf * 2);
    float* dis    = (float*)alloc((size_t)M * 4);
    int*   cnt    = (int*)alloc((size_t)M * 4);
    int*   rowptr = (int*)alloc((size_t)(M + 1) * 4);
    int*   cursor = (int*)alloc((size_t)M * 4);
    int*   bsum   = (int*)alloc(1024);
    int2*  csr    = (int2*)alloc((size_t)E * 8);
    int*   gstart  = (int*)alloc((size_t)(G + 1) * 4);

    // ---- CSR build + per-graph bounds
    hipMemsetAsync(cnt, 0, (size_t)M * 4, stream);
    deg_count<<<(E + 255) / 256, 256, 0, stream>>>(dst, cnt, E);
    block_scan<<<NB, 256, 0, stream>>>(cnt, rowptr, bsum, M);
    scan_bsum<<<1, 256, 0, stream>>>(bsum, NB);
    finalize_rowptr<<<NB, 256, 0, stream>>>(rowptr, cursor, bsum, cnt, dis, M, E);
    fill_csr<<<(E + 255) / 256, 256, 0, stream>>>(src, dst, dis, cursor, csr, E);
    graph_bounds<<<NB, 256, 0, stream>>>(batch, gstart, M, G);

    // ---- casts / weight prep
    cast_x<<<(M * Kp1 + 255) / 256, 256, 0, stream>>>(x, xb, M, F1, Kp1);
    prep_w<<<(Np1 * Kp1 + 255) / 256, 256, 0, stream>>>(W1, W1t, F1, F1, Kp1, Np1);
    prep_w<<<(Np2 * Kp2 + 255) / 256, 256, 0, stream>>>(W2, W2t, F1, F2, Kp2, Np2);
    prep_w<<<(Np3 * Kp3 + 255) / 256, 256, 0, stream>>>(W3, W3t, F2, F3, Kp3, Np3);
    prep_w<<<(Npf * Kpf + 255) / 256, 256, 0, stream>>>(Wfc, Wfct, F3, FC, Kpf, Npf);

    const int GG = (M + 3) / 4;
    const int GMX = (M + 63) / 64;

    // ---- layer 1: xb rows = 12 uint4; agg [M][96]; h1 = relu(agg@W1+b1) [M][80]
    gather_ilp<12, 5, 6, 12><<<GG, 256, 0, stream>>>((const uint4*)xb, rowptr, csr, dis, (uint4*)agg);
    gemm_mfma<0><<<dim3(GMX, Np1 / 64 + 1), 256, 0, stream>>>(agg, W1t, h1, nullptr, b1, nullptr, M, Kp1, Np1, F1);

    // ---- layer 2: h1 rows = 10 uint4; agg [M][96]; h2 = relu(agg@W2+b2) [M][160]
    gather_ilp<10, 6, 6, 12><<<GG, 256, 0, stream>>>((const uint4*)h1, rowptr, csr, dis, (uint4*)agg);
    gemm_mfma<0><<<dim3(GMX, Np2 / 64 + 1), 256, 0, stream>>>(agg, W2t, h2, nullptr, b2, nullptr, M, Kp2, Np2, F2);

    // ---- layer 3: h2 rows = 20 uint4; agg [M][160]; h3 = relu(agg@W3+b3) [M][320]
    gather_ilp<20, 3, 6, 20><<<GG, 256, 0, stream>>>((const uint4*)h2, rowptr, csr, dis, (uint4*)agg);
    gemm_mfma<0><<<dim3(GMX, Np3 / 64), 256, 0, stream>>>(agg, W3t, h3, nullptr, b3, nullptr, M, Kp3, Np3, F3);

    // ---- segmented max pool -> gb bf16 [G][320]
    pool_max_seg<<<G, 256, 0, stream>>>((const uint*)h3, gstart, (uint*)gb, Kpf / 2);

    // ---- FC: out = relu(gb@Wfc+bfc)+drug2, f32 [2048][489]
    gemm_mfma<1><<<dim3((G + 63) / 64, (Npf + 63) / 64), 256, 0, stream>>>(gb, Wfct, nullptr, out, bfc, drug2, G, Kpf, Npf, FC);
}

// Round 7
// 289.582 us; speedup vs baseline: 1.0214x; 1.0214x over previous
//
#include <hip/hip_runtime.h>

#define NNODES 50000
#define NEDGES 800000
#define NGRAPHS 2048

typedef __attribute__((ext_vector_type(8))) short bf16x8;
typedef __attribute__((ext_vector_type(4))) float f32x4;

__device__ __forceinline__ float bf2f(ushort u) {
    return __uint_as_float(((uint)u) << 16);
}
__device__ __forceinline__ ushort f2bf(float f) {
    uint u = __float_as_uint(f);
    return (ushort)((u + 0x7fff + ((u >> 16) & 1)) >> 16);  // RNE
}

// ---------------- degree ----------------
__global__ void deg_count(const int* __restrict__ dst, int* __restrict__ cnt, int E) {
    int e = blockIdx.x * blockDim.x + threadIdx.x;
    if (e < E) atomicAdd(&cnt[dst[e]], 1);
}

// ---------------- CSR build ----------------
__global__ void block_scan(const int* __restrict__ cnt, int* __restrict__ lp,
                           int* __restrict__ bsum, int M) {
    __shared__ int s[256];
    int t = threadIdx.x;
    int n = blockIdx.x * 256 + t;
    int v = (n < M) ? cnt[n] : 0;
    s[t] = v;
    __syncthreads();
    #pragma unroll
    for (int off = 1; off < 256; off <<= 1) {
        int u = (t >= off) ? s[t - off] : 0;
        __syncthreads();
        s[t] += u;
        __syncthreads();
    }
    if (n < M) lp[n] = s[t] - v;
    if (t == 255) bsum[blockIdx.x] = s[255];
}

__global__ void scan_bsum(int* __restrict__ bsum, int NB) {
    __shared__ int s[256];
    int t = threadIdx.x;
    int v = (t < NB) ? bsum[t] : 0;
    s[t] = v;
    __syncthreads();
    #pragma unroll
    for (int off = 1; off < 256; off <<= 1) {
        int u = (t >= off) ? s[t - off] : 0;
        __syncthreads();
        s[t] += u;
        __syncthreads();
    }
    if (t < NB) bsum[t] = s[t] - v;
}

// rowptr finalize + cursor init + dis = rsqrt(deg+1) fused
__global__ void finalize_rowptr(int* __restrict__ rowptr, int* __restrict__ cursor,
                                const int* __restrict__ bsum, const int* __restrict__ cnt,
                                float* __restrict__ dis, int M, int E) {
    int n = blockIdx.x * blockDim.x + threadIdx.x;
    if (n < M) {
        int v = rowptr[n] + bsum[n >> 8];
        rowptr[n] = v;
        cursor[n] = v;
        dis[n] = rsqrtf((float)(cnt[n] + 1));
    }
    if (n == 0) rowptr[M] = E;
}

// packed (src, norm) single 8B store per edge
__global__ void fill_csr(const int* __restrict__ src, const int* __restrict__ dst,
                         const float* __restrict__ dis, int* __restrict__ cursor,
                         int2* __restrict__ csr, int E) {
    int e = blockIdx.x * blockDim.x + threadIdx.x;
    if (e >= E) return;
    int s = src[e], d = dst[e];
    int pos = atomicAdd(&cursor[d], 1);
    csr[pos] = make_int2(s, __float_as_int(dis[s] * dis[d]));
}

// ---------------- input cast / weight prep ----------------
__global__ void cast_x(const float* __restrict__ x, ushort* __restrict__ xb,
                       int M, int K, int Kp) {
    int idx = blockIdx.x * blockDim.x + threadIdx.x;
    if (idx >= M * Kp) return;
    int n = idx / Kp, k = idx % Kp;
    xb[idx] = (k < K) ? f2bf(x[(size_t)n * K + k]) : (ushort)0;
}

// Wt[n][k] = W[k][n], bf16, zero-padded to [Np][Kp]
__global__ void prep_w(const float* __restrict__ W, ushort* __restrict__ Wt,
                       int K, int N, int Kp, int Np) {
    int idx = blockIdx.x * blockDim.x + threadIdx.x;
    if (idx >= Kp * Np) return;
    int n = idx / Kp, k = idx % Kp;
    Wt[idx] = (k < K && n < N) ? f2bf(W[(size_t)k * N + n]) : (ushort)0;
}

// ---------------- ILP gather (R5 structure): lanes = (sub-edge, uint4-chunk) ----
// 2 nodes per 128-thread block (1 wave per node) to cut tail imbalance and
// allow 32 waves/CU. U=4 interleaved per-lane predication (R5-proven best).
__device__ __forceinline__ void acc8(float* acc, uint4 v, float nm) {
    acc[0] += bf2f((ushort)(v.x & 0xffff)) * nm;
    acc[1] += bf2f((ushort)(v.x >> 16)) * nm;
    acc[2] += bf2f((ushort)(v.y & 0xffff)) * nm;
    acc[3] += bf2f((ushort)(v.y >> 16)) * nm;
    acc[4] += bf2f((ushort)(v.z & 0xffff)) * nm;
    acc[5] += bf2f((ushort)(v.z >> 16)) * nm;
    acc[6] += bf2f((ushort)(v.w & 0xffff)) * nm;
    acc[7] += bf2f((ushort)(v.w >> 16)) * nm;
}

template <int CH, int SUB, int CHOUT>
__global__ __launch_bounds__(128) void gather_ilp(const uint4* __restrict__ h,
                                                  const int* __restrict__ rowptr,
                                                  const int2* __restrict__ csr,
                                                  const float* __restrict__ dis,
                                                  uint4* __restrict__ agg) {
    int node = blockIdx.x * 2 + (threadIdx.x >> 6);
    if (node >= NNODES) return;
    int lane = threadIdx.x & 63;
    int sub = lane / CH;
    int ch = lane % CH;
    bool active = sub < SUB;

    float acc[8] = {};
    int beg = rowptr[node], end = rowptr[node + 1];
    for (int i = beg; i < end; i += 4 * SUB) {
        // phase 1: edge records (4 independent 8B loads)
        int2 ev[4];
        int vld[4];
        #pragma unroll
        for (int u = 0; u < 4; ++u) {
            int e = i + u * SUB + sub;
            vld[u] = active && (e < end);
            ev[u] = vld[u] ? csr[e] : make_int2(0, 0);
        }
        // phase 2: rows (4 independent 16B loads)
        uint4 av[4];
        #pragma unroll
        for (int u = 0; u < 4; ++u)
            av[u] = vld[u] ? h[(size_t)ev[u].x * CH + ch] : make_uint4(0, 0, 0, 0);
        // phase 3: accumulate (nm = 0 for invalid slots)
        #pragma unroll
        for (int u = 0; u < 4; ++u)
            acc8(acc, av[u], __int_as_float(ev[u].y));
    }

    // reduce partials across sub groups (read-only sources -> no contamination)
    float tot[8];
    #pragma unroll
    for (int j = 0; j < 8; ++j) tot[j] = acc[j];
    #pragma unroll
    for (int sb = 1; sb < SUB; ++sb) {
        int srcLane = ch + sb * CH;
        #pragma unroll
        for (int j = 0; j < 8; ++j) tot[j] += __shfl(acc[j], srcLane);
    }

    if (lane < CHOUT) {
        uint4 o = make_uint4(0, 0, 0, 0);
        if (lane < CH) {
            float di = dis[node];
            float d2 = di * di;
            uint4 hs = h[(size_t)node * CH + lane];
            tot[0] += bf2f((ushort)(hs.x & 0xffff)) * d2;
            tot[1] += bf2f((ushort)(hs.x >> 16)) * d2;
            tot[2] += bf2f((ushort)(hs.y & 0xffff)) * d2;
            tot[3] += bf2f((ushort)(hs.y >> 16)) * d2;
            tot[4] += bf2f((ushort)(hs.z & 0xffff)) * d2;
            tot[5] += bf2f((ushort)(hs.z >> 16)) * d2;
            tot[6] += bf2f((ushort)(hs.w & 0xffff)) * d2;
            tot[7] += bf2f((ushort)(hs.w >> 16)) * d2;
            o.x = (uint)f2bf(tot[0]) | ((uint)f2bf(tot[1]) << 16);
            o.y = (uint)f2bf(tot[2]) | ((uint)f2bf(tot[3]) << 16);
            o.z = (uint)f2bf(tot[4]) | ((uint)f2bf(tot[5]) << 16);
            o.w = (uint)f2bf(tot[6]) | ((uint)f2bf(tot[7]) << 16);
        }
        agg[(size_t)node * CHOUT + lane] = o;
    }
}

// ---------------- MFMA bf16 GEMM: C = epi(A[M][Kp] @ Wt[Np][Kp]^T) ----------------
template <int EPI>
__global__ __launch_bounds__(256) void gemm_mfma(const ushort* __restrict__ A,
                                                 const ushort* __restrict__ Bt,
                                                 ushort* __restrict__ Cb,
                                                 float* __restrict__ Cf,
                                                 const float* __restrict__ bias,
                                                 const float* __restrict__ addend,
                                                 int M, int Kp, int Np, int Nreal) {
    __shared__ ushort Asl[64 * 32];
    __shared__ ushort Bsl[64 * 32];
    const int tid = threadIdx.x;
    const int lane = tid & 63;
    const int wid = tid >> 6;
    const int wm = (wid >> 1) * 32, wn = (wid & 1) * 32;
    const int bm = blockIdx.x * 64, bn = blockIdx.y * 64;

    const int sr = tid >> 2;
    const int sc = tid & 3;
    const int swz = sc ^ ((sr >> 1) & 3);
    const int lc = lane >> 4;

    f32x4 acc[2][2] = {};
    for (int k0 = 0; k0 < Kp; k0 += 32) {
        bf16x8 av = {};
        int gr = bm + sr;
        if (gr < M) av = *(const bf16x8*)&A[(size_t)gr * Kp + k0 + sc * 8];
        *(bf16x8*)&Asl[sr * 32 + swz * 8] = av;
        bf16x8 bv = {};
        int gn = bn + sr;
        if (gn < Np) bv = *(const bf16x8*)&Bt[(size_t)gn * Kp + k0 + sc * 8];
        *(bf16x8*)&Bsl[sr * 32 + swz * 8] = bv;
        __syncthreads();
        bf16x8 af[2], bfr[2];
        #pragma unroll
        for (int m = 0; m < 2; ++m) {
            int r = wm + m * 16 + (lane & 15);
            int pc = lc ^ ((r >> 1) & 3);
            af[m] = *(const bf16x8*)&Asl[r * 32 + pc * 8];
        }
        #pragma unroll
        for (int n = 0; n < 2; ++n) {
            int r = wn + n * 16 + (lane & 15);
            int pc = lc ^ ((r >> 1) & 3);
            bfr[n] = *(const bf16x8*)&Bsl[r * 32 + pc * 8];
        }
        #pragma unroll
        for (int m = 0; m < 2; ++m)
            #pragma unroll
            for (int n = 0; n < 2; ++n)
                acc[m][n] = __builtin_amdgcn_mfma_f32_16x16x32_bf16(af[m], bfr[n], acc[m][n], 0, 0, 0);
        __syncthreads();
    }
    #pragma unroll
    for (int m = 0; m < 2; ++m) {
        #pragma unroll
        for (int n = 0; n < 2; ++n) {
            int gc = bn + wn + n * 16 + (lane & 15);
            #pragma unroll
            for (int j = 0; j < 4; ++j) {
                int gr = bm + wm + m * 16 + (lane >> 4) * 4 + j;
                if (gr >= M) continue;
                float v = acc[m][n][j];
                if (EPI == 0) {
                    if (gc < Np) {
                        float o = (gc < Nreal) ? fmaxf(v + bias[gc], 0.f) : 0.f;
                        Cb[(size_t)gr * Np + gc] = f2bf(o);
                    }
                } else {
                    if (gc < Nreal) {
                        float o = fmaxf(v + bias[gc], 0.f) + addend[(size_t)gr * Nreal + gc];
                        Cf[(size_t)gr * Nreal + gc] = o;
                    }
                }
            }
        }
    }
}

// ---------------- per-graph segment bounds (batch is sorted) ----------------
__global__ void graph_bounds(const int* __restrict__ batch, int* __restrict__ gstart,
                             int M, int G) {
    int n = blockIdx.x * blockDim.x + threadIdx.x;
    if (n >= M) return;
    int b = batch[n];
    int bp = (n == 0) ? -1 : batch[n - 1];
    for (int gg = bp + 1; gg <= b; ++gg) gstart[gg] = n;
    if (n == M - 1) {
        for (int gg = b + 1; gg <= G; ++gg) gstart[gg] = M;
    }
}

// ---------------- segmented max pool: block per graph, bf16 out ----------------
__global__ void pool_max_seg(const uint* __restrict__ h3, const int* __restrict__ gstart,
                             uint* __restrict__ gb, int PAIRS) {
    int g = blockIdx.x;
    int s = gstart[g], e = gstart[g + 1];
    for (int p = threadIdx.x; p < PAIRS; p += blockDim.x) {
        float mL = 0.f, mH = 0.f;  // h3 >= 0; empty graph -> 0 (isfinite guard)
        for (int n = s; n < e; ++n) {
            uint v = h3[(size_t)n * PAIRS + p];
            mL = fmaxf(mL, bf2f((ushort)(v & 0xffff)));
            mH = fmaxf(mH, bf2f((ushort)(v >> 16)));
        }
        gb[(size_t)g * PAIRS + p] = (uint)f2bf(mL) | ((uint)f2bf(mH) << 16);
    }
}

extern "C" void kernel_launch(void* const* d_in, const int* in_sizes, int n_in,
                              void* d_out, int out_size, void* d_ws, size_t ws_size,
                              hipStream_t stream) {
    const float* x     = (const float*)d_in[0];
    const int*   eidx  = (const int*)d_in[1];
    const int*   batch = (const int*)d_in[2];
    const float* drug2 = (const float*)d_in[3];
    const float* W1 = (const float*)d_in[4];
    const float* b1 = (const float*)d_in[5];
    const float* W2 = (const float*)d_in[6];
    const float* b2 = (const float*)d_in[7];
    const float* W3 = (const float*)d_in[8];
    const float* b3 = (const float*)d_in[9];
    const float* Wfc = (const float*)d_in[10];
    const float* bfc = (const float*)d_in[11];
    float* out = (float*)d_out;

    const int M = NNODES, E = NEDGES, G = NGRAPHS;
    const int F1 = 78, F2 = 156, F3 = 312, FC = 489;
    const int Kx = 80;                 // xb storage width (gather-1 source)
    const int Kp1 = 96, Np1 = 80;      // GEMM-1 K (agg padded), N
    const int Kp2 = 96, Np2 = 160;
    const int Kp3 = 160, Np3 = 320;
    const int Kpf = 320, Npf = 496;

    const int* src = eidx;
    const int* dst = eidx + E;
    const int NB = (M + 255) / 256;

    char* ws = (char*)d_ws;
    size_t off = 0;
    auto alloc = [&](size_t bytes) {
        void* p = ws + off;
        off += (bytes + 255) & ~(size_t)255;
        return p;
    };
    ushort* xb   = (ushort*)alloc((size_t)M * Kx * 2);
    ushort* h1   = (ushort*)alloc((size_t)M * Np1 * 2);
    ushort* h2   = (ushort*)alloc((size_t)M * Np2 * 2);
    ushort* h3   = (ushort*)alloc((size_t)M * Np3 * 2);
    ushort* agg  = (ushort*)alloc((size_t)M * Kp3 * 2);
    ushort* W1t  = (ushort*)alloc((size_t)Np1 * Kp1 * 2);
    ushort* W2t  = (ushort*)alloc((size_t)Np2 * Kp2 * 2);
    ushort* W3t  = (ushort*)alloc((size_t)Np3 * Kp3 * 2);
    ushort* Wfct = (ushort*)alloc((size_t)Npf * Kpf * 2);
    ushort* gb   = (ushort*)alloc((size_t)G * Kpf * 2);
    float* dis    = (float*)alloc((size_t)M * 4);
    int*   cnt    = (int*)alloc((size_t)M * 4);
    int*   rowptr = (int*)alloc((size_t)(M + 1) * 4);
    int*   cursor = (int*)alloc((size_t)M * 4);
    int*   bsum   = (int*)alloc(1024);
    int2*  csr    = (int2*)alloc((size_t)E * 8);
    int*   gstart  = (int*)alloc((size_t)(G + 1) * 4);

    // ---- CSR build + per-graph bounds
    hipMemsetAsync(cnt, 0, (size_t)M * 4, stream);
    deg_count<<<(E + 255) / 256, 256, 0, stream>>>(dst, cnt, E);
    block_scan<<<NB, 256, 0, stream>>>(cnt, rowptr, bsum, M);
    scan_bsum<<<1, 256, 0, stream>>>(bsum, NB);
    finalize_rowptr<<<NB, 256, 0, stream>>>(rowptr, cursor, bsum, cnt, dis, M, E);
    fill_csr<<<(E + 255) / 256, 256, 0, stream>>>(src, dst, dis, cursor, csr, E);
    graph_bounds<<<NB, 256, 0, stream>>>(batch, gstart, M, G);

    // ---- casts / weight prep
    cast_x<<<(M * Kx + 255) / 256, 256, 0, stream>>>(x, xb, M, F1, Kx);
    prep_w<<<(Np1 * Kp1 + 255) / 256, 256, 0, stream>>>(W1, W1t, F1, F1, Kp1, Np1);
    prep_w<<<(Np2 * Kp2 + 255) / 256, 256, 0, stream>>>(W2, W2t, F1, F2, Kp2, Np2);
    prep_w<<<(Np3 * Kp3 + 255) / 256, 256, 0, stream>>>(W3, W3t, F2, F3, Kp3, Np3);
    prep_w<<<(Npf * Kpf + 255) / 256, 256, 0, stream>>>(Wfc, Wfct, F3, FC, Kpf, Npf);

    const int GG = (M + 1) / 2;       // 2 nodes per 128-thread block
    const int GMX = (M + 63) / 64;

    // ---- layer 1: xb rows = 10 uint4; agg [M][96]; h1 = relu(agg@W1+b1) [M][80]
    gather_ilp<10, 6, 12><<<GG, 128, 0, stream>>>((const uint4*)xb, rowptr, csr, dis, (uint4*)agg);
    gemm_mfma<0><<<dim3(GMX, Np1 / 64 + 1), 256, 0, stream>>>(agg, W1t, h1, nullptr, b1, nullptr, M, Kp1, Np1, F1);

    // ---- layer 2: h1 rows = 10 uint4; agg [M][96]; h2 = relu(agg@W2+b2) [M][160]
    gather_ilp<10, 6, 12><<<GG, 128, 0, stream>>>((const uint4*)h1, rowptr, csr, dis, (uint4*)agg);
    gemm_mfma<0><<<dim3(GMX, Np2 / 64 + 1), 256, 0, stream>>>(agg, W2t, h2, nullptr, b2, nullptr, M, Kp2, Np2, F2);

    // ---- layer 3: h2 rows = 20 uint4; agg [M][160]; h3 = relu(agg@W3+b3) [M][320]
    gather_ilp<20, 3, 20><<<GG, 128, 0, stream>>>((const uint4*)h2, rowptr, csr, dis, (uint4*)agg);
    gemm_mfma<0><<<dim3(GMX, Np3 / 64), 256, 0, stream>>>(agg, W3t, h3, nullptr, b3, nullptr, M, Kp3, Np3, F3);

    // ---- segmented max pool -> gb bf16 [G][320]
    pool_max_seg<<<G, 256, 0, stream>>>((const uint*)h3, gstart, (uint*)gb, Kpf / 2);

    // ---- FC: out = relu(gb@Wfc+bfc)+drug2, f32 [2048][489]
    gemm_mfma<1><<<dim3((G + 63) / 64, (Npf + 63) / 64), 256, 0, stream>>>(gb, Wfct, nullptr, out, bfc, drug2, G, Kpf, Npf, FC);
}